// Round 8
// baseline (178.028 us; speedup 1.0000x reference)
//
#include <hip/hip_runtime.h>
#include <math.h>

namespace {

constexpr int B = 4;
constexpr int C = 512;
constexpr int NH = 32;          // heads
constexpr int CPH = 16;         // channels per head
constexpr int N = 32 * 32 * 32; // 32768 spatial
constexpr int NJ = 32;          // n-chunks (1024) per (b,h)
constexpr int NREC = NJ * 4 * 4;  // row-records per (b,h): 32 blocks x 4 waves x 4 rows = 512
constexpr long YSIZE = (long)B * C * N;  // 67,108,864

typedef float f4v __attribute__((ext_vector_type(4)));

__device__ inline float wrs(float v) {
#pragma unroll
  for (int o = 32; o > 0; o >>= 1) v += __shfl_xor(v, o);
  return v;
}

// 16-lane row sum entirely on the VALU pipe: quad_perm xor1, xor2, then
// row_ror:4, row_ror:8. After these 4 dpp-adds EVERY lane of the row holds
// the full 16-lane sum. No shfl / ds_bpermute (LDS pipe) at all.
template <int CTRL>
__device__ __forceinline__ float dppAdd(float v) {
  const int r = __builtin_amdgcn_update_dpp(
      0, __float_as_int(v), CTRL, 0xF, 0xF, true);
  return v + __int_as_float(r);
}
__device__ __forceinline__ float rowSum16(float v) {
  v = dppAdd<0xB1>(v);    // quad_perm(1,0,3,2): + lane^1
  v = dppAdd<0x4E>(v);    // quad_perm(2,3,0,1): + lane^2
  v = dppAdd<0x124>(v);   // row_ror:4
  v = dppAdd<0x128>(v);   // row_ror:8 -> full 16-lane row sum
  return v;
}

// ---------------------------------------------------------------------------
// kA: single HBM pass over x. grid (32, NH, B) = 4096 blocks, 256 threads.
// Block = 1024 consecutive n of one (b,h). 16 channel float4 loads issued as
// one independent batch into a register tile; logits (no max-shift: ~unit
// variance, fp32 exp safe to 88); exp; weighted sums. Reduction stops at the
// 16-lane ROW level (pure VALU DPP): lane row*16+p keeps {dK[p], dQ[p],
// cs[p], (p==0?sKrow : p==1?sQrow : 0)} and the wave stores 4 row-records =
// one contiguous 1 KB dwordx4 burst. Zero cross-lane shfl, zero LDS, no
// barriers. Biases & -mu*w cancel in softmax; sum_n attn = 1 folds mean
// subtraction into k4.
__global__ __launch_bounds__(256, 4) void kA(const float* __restrict__ x,
                                             const float* __restrict__ kw,
                                             const float* __restrict__ qw,
                                             float* __restrict__ prec) {
  const int b = blockIdx.z, h = blockIdx.y, j = blockIdx.x;
  const int t = threadIdx.x, lane = t & 63, wid = t >> 6;
  const int p = lane & 15;
  const float* xs = x + ((long)(b * C + h * CPH)) * N + (long)j * 1024 + t * 4;

  // batched independent loads -> register tile
  float4 xv[CPH];
#pragma unroll
  for (int c = 0; c < CPH; ++c) xv[c] = *(const float4*)(xs + (long)c * N);

  float4 lk = make_float4(0.f, 0.f, 0.f, 0.f);
  float4 lq = make_float4(0.f, 0.f, 0.f, 0.f);
#pragma unroll
  for (int c = 0; c < CPH; ++c) {
    const float wkc = kw[h * CPH + c], wqc = qw[h * CPH + c];
    lk.x += xv[c].x * wkc; lk.y += xv[c].y * wkc;
    lk.z += xv[c].z * wkc; lk.w += xv[c].w * wkc;
    lq.x += xv[c].x * wqc; lq.y += xv[c].y * wqc;
    lq.z += xv[c].z * wqc; lq.w += xv[c].w * wqc;
  }
  const float4 ek = make_float4(__expf(lk.x), __expf(lk.y),
                                __expf(lk.z), __expf(lk.w));
  const float4 eq = make_float4(__expf(lq.x), __expf(lq.y),
                                __expf(lq.z), __expf(lq.w));
  const float sKr = rowSum16((ek.x + ek.y) + (ek.z + ek.w));
  const float sQr = rowSum16((eq.x + eq.y) + (eq.z + eq.w));

  float o0 = 0.f, o1 = 0.f, o2 = 0.f, o3 = 0.f;
#pragma unroll
  for (int c = 0; c < CPH; ++c) {
    float dk = (xv[c].x * ek.x + xv[c].y * ek.y) + (xv[c].z * ek.z + xv[c].w * ek.w);
    float dq = (xv[c].x * eq.x + xv[c].y * eq.y) + (xv[c].z * eq.z + xv[c].w * eq.w);
    float cs = (xv[c].x + xv[c].y) + (xv[c].z + xv[c].w);
    dk = rowSum16(dk);
    dq = rowSum16(dq);
    cs = rowSum16(cs);
    if (p == c) { o0 = dk; o1 = dq; o2 = cs; }
  }
  if (p == 0) o3 = sKr;
  if (p == 1) o3 = sQr;

  // row-record: ((b,h) panel, j, wave, row) -> 64 floats laid out [p][4].
  // Wave store = 64 lanes x float4 contiguous (1 KB burst).
  const long ridx = ((((long)(b * NH + h)) * NJ + j) * 4 + wid) * 4 + (lane >> 4);
  f4v r; r.x = o0; r.y = o1; r.z = o2; r.w = o3;
  *(f4v*)(prec + ridx * 64 + p * 4) = r;
}

// ---------------------------------------------------------------------------
// k4: combine row-records + finalize. grid(B), 512 threads (thread=channel).
__global__ __launch_bounds__(512) void k4(const float* __restrict__ prec,
                                          const float* __restrict__ pw1,
                                          const float* __restrict__ pb1,
                                          const float* __restrict__ pw2,
                                          const float* __restrict__ pb2,
                                          float* __restrict__ scale,
                                          float* __restrict__ offset,
                                          float* __restrict__ dpOut) {
  const int b = blockIdx.x;
  const int c = threadIdx.x;           // 0..511
  const int h = c >> 4, i = c & 15;
  const float4* rec4 = (const float4*)prec + ((long)(b * NH + h)) * NREC * 16;

  float dk = 0.f, dq = 0.f, cs = 0.f, sacc = 0.f;
  for (int j = 0; j < NREC; ++j) {
    const float4 r = rec4[j * 16 + i];
    dk += r.x; dq += r.y; cs += r.z; sacc += r.w;  // r.w: sK rows at i==0, sQ at i==1, else 0
  }
  __shared__ float skS[NH], sqS[NH];
  if (i == 0) skS[h] = sacc;
  if (i == 1) sqS[h] = sacc;
  __syncthreads();
  const float sk = skS[h], sq = sqS[h];

  const float mu = cs * (1.f / N);
  const float Kv = dk / sk - mu;
  const float Qv = dq / sq - mu;

  __shared__ float muS[C], h1S[256];
  muS[c] = mu;
  __syncthreads();
  if (c < 256) {
    const int g = c >> 3;
    float a = pb1[c];
#pragma unroll
    for (int k = 0; k < 16; ++k) a += muS[g * 16 + k] * pw1[c * 16 + k];
    h1S[c] = fmaxf(a, 0.f);
  }
  __syncthreads();
  float a = pb2[c];
  const int g2 = c >> 4;
#pragma unroll
  for (int k = 0; k < 8; ++k) a += h1S[g2 * 8 + k] * pw2[c * 8 + k];
  const float P = 1.f / (1.f + __expf(-a));
  scale[b * C + c] = P;
  offset[b * C + c] = (Kv - Qv) * P;

  float pdp = wrs(Kv * Qv);
  __shared__ float pS[8];
  const int lane = c & 63, wid = c >> 6;
  if (lane == 0) pS[wid] = pdp;
  __syncthreads();
  if (c == 0) {
    float tot = 0.f;
    for (int w = 0; w < 8; ++w) tot += pS[w];
    dpOut[b] = tot * (1.f / C);
  }
}

// ---------------------------------------------------------------------------
// k5: y = x * scale[b,c] + offset[b,c]. grid (N/4096, C, B), block 256.
// REVERSED traversal: kA streamed x front-to-back through the 256 MiB L3
// (x is exactly L3-sized). Reading forward again is the LRU worst case
// (oldest lines evicted first). Reading BACKWARD rides the LRU frontier:
// freshest lines first. y stores are nontemporal so the write stream
// doesn't evict x.
__global__ __launch_bounds__(256) void k5(const float* __restrict__ x,
                                          const float* __restrict__ scale,
                                          const float* __restrict__ offset,
                                          float* __restrict__ y) {
  const int b = B - 1 - (int)blockIdx.z;
  const int cc = C - 1 - (int)blockIdx.y;
  const int jr = (N / 4096 - 1) - (int)blockIdx.x;
  const int t = threadIdx.x;
  const long base = ((long)(b * C + cc)) * N + (long)jr * 4096;
  const float s = scale[b * C + cc], o = offset[b * C + cc];
#pragma unroll
  for (int k = 0; k < 4; ++k) {
    const long i = base + (long)(k * 256 + t) * 4;
    const float4 v = *(const float4*)(x + i);
    f4v w;
    w.x = v.x * s + o; w.y = v.y * s + o;
    w.z = v.z * s + o; w.w = v.w * s + o;
    __builtin_nontemporal_store(w, (f4v*)(y + i));
  }
}

} // namespace

extern "C" void kernel_launch(void* const* d_in, const int* in_sizes, int n_in,
                              void* d_out, int out_size, void* d_ws, size_t ws_size,
                              hipStream_t stream) {
  const float* x   = (const float*)d_in[0];
  const float* pw1 = (const float*)d_in[1];
  const float* pb1 = (const float*)d_in[2];
  const float* pw2 = (const float*)d_in[3];
  const float* pb2 = (const float*)d_in[4];
  const float* kw  = (const float*)d_in[5];
  // d_in[6]=kb, d_in[8]=qb unused: biases cancel in softmax (shift-invariant),
  // and sum_n attn = 1 folds mean-subtraction into the finalize step.
  const float* qw  = (const float*)d_in[7];
  float* out = (float*)d_out;
  float* ws  = (float*)d_ws;

  // scale/offset always in ws (read by k5 while k5 writes out)
  float* scale  = ws;          // 2048
  float* offset = ws + 2048;   // 2048

  // row-records: B*NH*NREC*64 = 4,194,304 floats (16 MB)
  constexpr long PREC = (long)B * NH * NREC * 64;
  float* prec;
  if (ws_size >= (size_t)(4096 + PREC) * sizeof(float)) {
    prec = ws + 4096;
  } else {
    prec = out;  // consumed by k4 before k5 overwrites out
  }

  hipLaunchKernelGGL(kA, dim3(NJ, NH, B), dim3(256), 0, stream,
                     x, kw, qw, prec);
  hipLaunchKernelGGL(k4, dim3(B), dim3(C), 0, stream,
                     prec, pw1, pb1, pw2, pb2, scale, offset, out + YSIZE);
  hipLaunchKernelGGL(k5, dim3(N / 4096, C, B), dim3(256), 0, stream,
                     x, scale, offset, out);
}

// Round 9
// 144.320 us; speedup vs baseline: 1.2336x; 1.2336x over previous
//
#include <hip/hip_runtime.h>
#include <math.h>

namespace {

constexpr int B = 4;
constexpr int C = 512;
constexpr int NH = 32;          // heads
constexpr int CPH = 16;         // channels per head
constexpr int N = 32 * 32 * 32; // 32768 spatial
constexpr int NJ = 32;          // n-chunks (1024) per (b,h)
constexpr int NREC = NJ * 4;    // wave-records per (b,h): 32 blocks x 4 waves
constexpr long YSIZE = (long)B * C * N;  // 67,108,864

typedef float f4v __attribute__((ext_vector_type(4)));

__device__ inline float wrs(float v) {
#pragma unroll
  for (int o = 32; o > 0; o >>= 1) v += __shfl_xor(v, o);
  return v;
}

// DPP add with compile-time control and row mask. Disabled rows get old=0
// added -> unchanged.
template <int CTRL, int RM = 0xF>
__device__ __forceinline__ float dppAdd(float v) {
  const int r = __builtin_amdgcn_update_dpp(
      0, __float_as_int(v), CTRL, RM, 0xF, true);
  return v + __int_as_float(r);
}
// Full 64-lane sum entirely on the VALU pipe (zero LDS-pipe ops):
// 4 intra-row steps (all lanes hold row sum), then masked row_bcast15
// (rows 1,3 += prev row) and row_bcast31 (rows 2,3 += lower half).
// Total valid in ROW 3 (lanes 48-63) only.
__device__ __forceinline__ float waveSumRow3(float v) {
  v = dppAdd<0xB1>(v);          // quad_perm(1,0,3,2): + lane^1
  v = dppAdd<0x4E>(v);          // quad_perm(2,3,0,1): + lane^2
  v = dppAdd<0x124>(v);         // row_ror:4
  v = dppAdd<0x128>(v);         // row_ror:8 -> 16-lane row sum, all lanes
  v = dppAdd<0x142, 0xA>(v);    // row_bcast15: rows 1,3 += rows 0,2
  v = dppAdd<0x143, 0xC>(v);    // row_bcast31: rows 2,3 += rows 0+1
  return v;                     // row 3 = full wave sum
}

// ---------------------------------------------------------------------------
// kA: single HBM pass over x. grid (32, NH, B) = 4096 blocks, 256 threads.
// Block = 1024 consecutive n of one (b,h). 16 channel float4 loads issued as
// one independent batch into a register tile; logits (no max-shift: ~unit
// variance, fp32 exp safe to 88); exp; weighted sums. Reduction: full
// 64-lane sum per value via pure-VALU DPP chain (waveSumRow3); lane 48+c
// keeps {dK[c], dQ[c], cs[c], s} and row 3 stores one 16-float4 record
// (256 B) per wave. ZERO cross-lane LDS-pipe ops, no LDS, no barriers.
// Biases & -mu*w cancel in softmax; sum_n attn = 1 folds mean subtraction
// into k4.
__global__ __launch_bounds__(256, 4) void kA(const float* __restrict__ x,
                                             const float* __restrict__ kw,
                                             const float* __restrict__ qw,
                                             float* __restrict__ prec) {
  const int b = blockIdx.z, h = blockIdx.y, j = blockIdx.x;
  const int t = threadIdx.x, lane = t & 63, wid = t >> 6;
  const int p = lane & 15;
  const float* xs = x + ((long)(b * C + h * CPH)) * N + (long)j * 1024 + t * 4;

  // batched independent loads -> register tile
  float4 xv[CPH];
#pragma unroll
  for (int c = 0; c < CPH; ++c) xv[c] = *(const float4*)(xs + (long)c * N);

  float4 lk = make_float4(0.f, 0.f, 0.f, 0.f);
  float4 lq = make_float4(0.f, 0.f, 0.f, 0.f);
#pragma unroll
  for (int c = 0; c < CPH; ++c) {
    const float wkc = kw[h * CPH + c], wqc = qw[h * CPH + c];
    lk.x += xv[c].x * wkc; lk.y += xv[c].y * wkc;
    lk.z += xv[c].z * wkc; lk.w += xv[c].w * wkc;
    lq.x += xv[c].x * wqc; lq.y += xv[c].y * wqc;
    lq.z += xv[c].z * wqc; lq.w += xv[c].w * wqc;
  }
  const float4 ek = make_float4(__expf(lk.x), __expf(lk.y),
                                __expf(lk.z), __expf(lk.w));
  const float4 eq = make_float4(__expf(lq.x), __expf(lq.y),
                                __expf(lq.z), __expf(lq.w));
  const float sK = waveSumRow3((ek.x + ek.y) + (ek.z + ek.w));
  const float sQ = waveSumRow3((eq.x + eq.y) + (eq.z + eq.w));

  float o0 = 0.f, o1 = 0.f, o2 = 0.f;
#pragma unroll
  for (int c = 0; c < CPH; ++c) {
    float dk = (xv[c].x * ek.x + xv[c].y * ek.y) + (xv[c].z * ek.z + xv[c].w * ek.w);
    float dq = (xv[c].x * eq.x + xv[c].y * eq.y) + (xv[c].z * eq.z + xv[c].w * eq.w);
    float cs = (xv[c].x + xv[c].y) + (xv[c].z + xv[c].w);
    dk = waveSumRow3(dk);
    dq = waveSumRow3(dq);
    cs = waveSumRow3(cs);
    if (p == c) { o0 = dk; o1 = dq; o2 = cs; }
  }
  const float o3 = (p == 0) ? sK : ((p == 1) ? sQ : 0.f);

  if ((lane >> 4) == 3) {  // row 3 holds the valid wave totals
    const long ridx = (((long)(b * NH + h)) * NJ + j) * 4 + wid;
    f4v r; r.x = o0; r.y = o1; r.z = o2; r.w = o3;
    *(f4v*)(prec + ridx * 64 + p * 4) = r;
  }
}

// ---------------------------------------------------------------------------
// k4: combine wave-records + finalize. grid(B), 512 threads (thread=channel).
// prec = 4 MB total, 1 MB per block (R7 volume).
__global__ __launch_bounds__(512) void k4(const float* __restrict__ prec,
                                          const float* __restrict__ pw1,
                                          const float* __restrict__ pb1,
                                          const float* __restrict__ pw2,
                                          const float* __restrict__ pb2,
                                          float* __restrict__ scale,
                                          float* __restrict__ offset,
                                          float* __restrict__ dpOut) {
  const int b = blockIdx.x;
  const int c = threadIdx.x;           // 0..511
  const int h = c >> 4, i = c & 15;
  const float4* rec4 = (const float4*)prec + ((long)(b * NH + h)) * NREC * 16;

  float dk = 0.f, dq = 0.f, cs = 0.f, sacc = 0.f;
  for (int j = 0; j < NREC; ++j) {
    const float4 r = rec4[j * 16 + i];
    dk += r.x; dq += r.y; cs += r.z; sacc += r.w;  // r.w: sK at i==0, sQ at i==1
  }
  __shared__ float skS[NH], sqS[NH];
  if (i == 0) skS[h] = sacc;
  if (i == 1) sqS[h] = sacc;
  __syncthreads();
  const float sk = skS[h], sq = sqS[h];

  const float mu = cs * (1.f / N);
  const float Kv = dk / sk - mu;
  const float Qv = dq / sq - mu;

  __shared__ float muS[C], h1S[256];
  muS[c] = mu;
  __syncthreads();
  if (c < 256) {
    const int g = c >> 3;
    float a = pb1[c];
#pragma unroll
    for (int k = 0; k < 16; ++k) a += muS[g * 16 + k] * pw1[c * 16 + k];
    h1S[c] = fmaxf(a, 0.f);
  }
  __syncthreads();
  float a = pb2[c];
  const int g2 = c >> 4;
#pragma unroll
  for (int k = 0; k < 8; ++k) a += h1S[g2 * 8 + k] * pw2[c * 8 + k];
  const float P = 1.f / (1.f + __expf(-a));
  scale[b * C + c] = P;
  offset[b * C + c] = (Kv - Qv) * P;

  float pdp = wrs(Kv * Qv);
  __shared__ float pS[8];
  const int lane = c & 63, wid = c >> 6;
  if (lane == 0) pS[wid] = pdp;
  __syncthreads();
  if (c == 0) {
    float tot = 0.f;
    for (int w = 0; w < 8; ++w) tot += pS[w];
    dpOut[b] = tot * (1.f / C);
  }
}

// ---------------------------------------------------------------------------
// k5: y = x * scale[b,c] + offset[b,c]. grid (N/4096, C, B), block 256.
// Forward traversal (R8's reversal unproven), nontemporal y stores so the
// write stream doesn't evict x from L3.
__global__ __launch_bounds__(256) void k5(const float* __restrict__ x,
                                          const float* __restrict__ scale,
                                          const float* __restrict__ offset,
                                          float* __restrict__ y) {
  const int b = blockIdx.z, cc = blockIdx.y;
  const int t = threadIdx.x;
  const long base = ((long)(b * C + cc)) * N + (long)blockIdx.x * 4096;
  const float s = scale[b * C + cc], o = offset[b * C + cc];
#pragma unroll
  for (int k = 0; k < 4; ++k) {
    const long i = base + (long)(k * 256 + t) * 4;
    const float4 v = *(const float4*)(x + i);
    f4v w;
    w.x = v.x * s + o; w.y = v.y * s + o;
    w.z = v.z * s + o; w.w = v.w * s + o;
    __builtin_nontemporal_store(w, (f4v*)(y + i));
  }
}

} // namespace

extern "C" void kernel_launch(void* const* d_in, const int* in_sizes, int n_in,
                              void* d_out, int out_size, void* d_ws, size_t ws_size,
                              hipStream_t stream) {
  const float* x   = (const float*)d_in[0];
  const float* pw1 = (const float*)d_in[1];
  const float* pb1 = (const float*)d_in[2];
  const float* pw2 = (const float*)d_in[3];
  const float* pb2 = (const float*)d_in[4];
  const float* kw  = (const float*)d_in[5];
  // d_in[6]=kb, d_in[8]=qb unused: biases cancel in softmax (shift-invariant),
  // and sum_n attn = 1 folds mean-subtraction into the finalize step.
  const float* qw  = (const float*)d_in[7];
  float* out = (float*)d_out;
  float* ws  = (float*)d_ws;

  // scale/offset always in ws (read by k5 while k5 writes out)
  float* scale  = ws;          // 2048
  float* offset = ws + 2048;   // 2048

  // wave-records: B*NH*NREC*64 = 1,048,576 floats (4 MB)
  constexpr long PREC = (long)B * NH * NREC * 64;
  float* prec;
  if (ws_size >= (size_t)(4096 + PREC) * sizeof(float)) {
    prec = ws + 4096;
  } else {
    prec = out;  // consumed by k4 before k5 overwrites out
  }

  hipLaunchKernelGGL(kA, dim3(NJ, NH, B), dim3(256), 0, stream,
                     x, kw, qw, prec);
  hipLaunchKernelGGL(k4, dim3(B), dim3(C), 0, stream,
                     prec, pw1, pb1, pw2, pb2, scale, offset, out + YSIZE);
  hipLaunchKernelGGL(k5, dim3(N / 4096, C, B), dim3(256), 0, stream,
                     x, scale, offset, out);
}